// Round 13
// baseline (294.191 us; speedup 1.0000x reference)
//
#include <hip/hip_runtime.h>
#include <hip/hip_bf16.h>
#include <type_traits>

// Problem constants
#define NN 50000
#define EE 800000
#define HH 4
#define DD 64
#define HD 256
#define DIN 128

typedef _Float16 f16x8 __attribute__((ext_vector_type(8)));
typedef float f32x4 __attribute__((ext_vector_type(4)));

__device__ inline ushort f2h(float x) {
    _Float16 h = (_Float16)x;
    return __builtin_bit_cast(ushort, h);
}
__device__ inline float h2f(ushort u) {
    return (float)__builtin_bit_cast(_Float16, u);
}

// async global->LDS, 16B per lane; LDS base must be wave-uniform, global per-lane
__device__ inline void gload16(const ushort* src, ushort* lds_dst) {
    __builtin_amdgcn_global_load_lds(
        (const __attribute__((address_space(1))) void*)src,
        (__attribute__((address_space(3))) void*)lds_dst, 16, 0, 0);
}

// ---------------- fused prep: edge histogram + f32->f16 converts ----------------
// blocks [0, HB): histogram of e0 into cnt (cnt pre-zeroed)
// blocks [HB, HB+CB): convert x -> xf, W0 -> w0f, W1 -> w1f (float4 granules)

#define HB 3125                      // (EE+255)/256
#define NX4 (NN * DIN / 4)           // 1,600,000
#define NW04 (HD * DIN / 4)          // 8,192
#define NW14 (HD * HD / 4)           // 16,384
#define CB ((NX4 + NW04 + NW14 + 255) / 256)  // 6,346

__global__ void prep_kernel(const int* __restrict__ e0, int* __restrict__ cnt,
                            const float* __restrict__ x, ushort* __restrict__ xf,
                            const float* __restrict__ W0, ushort* __restrict__ w0f,
                            const float* __restrict__ W1, ushort* __restrict__ w1f) {
    const int b = blockIdx.x;
    if (b < HB) {
        int i = b * 256 + threadIdx.x;
        if (i < EE) atomicAdd(&cnt[e0[i]], 1);
        return;
    }
    int i = (b - HB) * 256 + threadIdx.x;
    const float* src;
    ushort* dst;
    if (i < NX4) {
        src = x; dst = xf;
    } else if (i < NX4 + NW04) {
        i -= NX4; src = W0; dst = w0f;
    } else {
        i -= NX4 + NW04;
        if (i >= NW14) return;
        src = W1; dst = w1f;
    }
    float4 v = ((const float4*)src)[i];
    ushort4 h;
    h.x = f2h(v.x); h.y = f2h(v.y); h.z = f2h(v.z); h.w = f2h(v.w);
    ((ushort4*)dst)[i] = h;
}

// ---------------- CSR scan ----------------

__global__ __launch_bounds__(1024) void scanA_kernel(const int* __restrict__ cnt,
                                                     int* __restrict__ incl,
                                                     int* __restrict__ tot, int N) {
    __shared__ int buf[2][1024];
    int b = blockIdx.x, t = threadIdx.x;
    int i = b * 1024 + t;
    int v = (i < N) ? cnt[i] : 0;
    buf[0][t] = v;
    __syncthreads();
    int sel = 0;
    for (int off = 1; off < 1024; off <<= 1) {
        int nv = buf[sel][t];
        if (t >= off) nv += buf[sel][t - off];
        buf[sel ^ 1][t] = nv;
        __syncthreads();
        sel ^= 1;
    }
    if (i < N) incl[i] = buf[sel][t];
    if (t == 1023) tot[b] = buf[sel][1023];
}

// scanC: adds inline prefix of block totals (<=48 L2-hot adds per thread)
__global__ void scanC_kernel(const int* __restrict__ incl, const int* __restrict__ tot,
                             const int* __restrict__ cnt, int* __restrict__ rp,
                             int* __restrict__ cur, int N) {
    int i = blockIdx.x * 256 + threadIdx.x;
    if (i == 0) rp[0] = 0;
    if (i < N) {
        int blk = i >> 10;
        int off = 0;
        for (int b = 0; b < blk; ++b) off += tot[b];
        int e = incl[i] + off;
        rp[i + 1] = e;
        cur[i] = e - cnt[i];
    }
}

__global__ void scatter_kernel(const int* __restrict__ e0, const int* __restrict__ e1,
                               int* __restrict__ cur, int* __restrict__ col, int E) {
    int i = blockIdx.x * 256 + threadIdx.x;
    if (i < E) {
        int pos = atomicAdd(&cur[e0[i]], 1);
        col[pos] = e1[i];
    }
}

// ---------------- MFMA GEMM (f16) + fused right-score epilogue ----------------
// Y[n][m] = sum_k A[n][k]*W[m][k] + b[m]   (f16 operands, f32 accum)
// bw[n][h] = exp( (sum_d lrelu(Y[n][h*64+d]*att_r[h][d])) / 128 )
// Block: 128 rows x 256 cols, BK=32, double-buffered LDS (2x24KB), col-split
// waves (wave w owns cols [w*64,w*64+64) = head w). Per K-step per wave:
// 12 ds_read_b128 vs 32 MFMA -> MFMA-bound. T3/T4 pipeline: STAGE(next) ->
// s_waitcnt vmcnt(6) (counted: 6 loads/wave/tile) -> s_barrier -> COMPUTE(cur)
// -> s_barrier. LDS layout [kchunk(4)][row][8k]: linear for global_load_lds,
// conflict-free for ds_read_b128 fragments.

template <int K>
__global__ __launch_bounds__(256) void gemm_mfma(const ushort* __restrict__ A,
                                                 const ushort* __restrict__ B,
                                                 const float* __restrict__ bias,
                                                 const float* __restrict__ att,
                                                 ushort* __restrict__ Y,
                                                 float* __restrict__ bw,
                                                 int Nrows) {
    __shared__ ushort sh[2][12288];  // per buf: A[4][128][8] (4096) + B[4][256][8] (8192)

    const int t = threadIdx.x;
    const int w = t >> 6, lane = t & 63;
    const int lg = lane >> 4;
    const int lm = lane & 15;
    const int row0 = blockIdx.x * 128;

    f32x4 acc[8][4];  // [rowblock][colblock]; cols = w*64 + cb*16 + lm
#pragma unroll
    for (int rb = 0; rb < 8; ++rb)
#pragma unroll
        for (int cb = 0; cb < 4; ++cb) acc[rb][cb] = (f32x4){0.f, 0.f, 0.f, 0.f};

    auto STAGE = [&](int b, int ks) {  // 6 global_load_lds per wave
        const int k0 = ks * 32;
        ushort* base = sh[b];
        gload16(A + (size_t)(row0 + lane) * K + k0 + w * 8, base + w * 1024);
        gload16(A + (size_t)(row0 + 64 + lane) * K + k0 + w * 8, base + w * 1024 + 512);
#pragma unroll
        for (int j2 = 0; j2 < 4; ++j2)
            gload16(B + (size_t)(j2 * 64 + lane) * K + k0 + w * 8,
                    base + 4096 + w * 2048 + j2 * 512);
    };
    auto COMPUTE = [&](int b) {
        ushort* base = sh[b];
        f16x8 a_h[8], b_h[4];
#pragma unroll
        for (int rb = 0; rb < 8; ++rb)
            a_h[rb] = *(const f16x8*)(base + lg * 1024 + (rb * 16 + lm) * 8);
#pragma unroll
        for (int cb = 0; cb < 4; ++cb) {
            const int c = w * 64 + cb * 16 + lm;
            b_h[cb] = *(const f16x8*)(base + 4096 + lg * 2048 + c * 8);
        }
#pragma unroll
        for (int rb = 0; rb < 8; ++rb)
#pragma unroll
            for (int cb = 0; cb < 4; ++cb)
                acc[rb][cb] = __builtin_amdgcn_mfma_f32_16x16x32_f16(
                    a_h[rb], b_h[cb], acc[rb][cb], 0, 0, 0);
    };

    constexpr int NT = K / 32;
    STAGE(0, 0);
#pragma unroll
    for (int ks = 0; ks < NT; ++ks) {
        const int cb_ = ks & 1;
        if (ks + 1 < NT) {
            STAGE(cb_ ^ 1, ks + 1);
            asm volatile("s_waitcnt vmcnt(6)" ::: "memory");  // cur tile landed
        } else {
            asm volatile("s_waitcnt vmcnt(0)" ::: "memory");
        }
        __builtin_amdgcn_s_barrier();
        COMPUTE(cb_);
        __builtin_amdgcn_s_barrier();  // reads done before next STAGE overwrites
    }

    // ---- epilogue: bias, f16 store, fused right-scores (wave w = head w) ----
    float attr[4], bv[4];
#pragma unroll
    for (int cb = 0; cb < 4; ++cb) {
        attr[cb] = att[w * 128 + 64 + cb * 16 + lm];
        bv[cb] = bias[w * 64 + cb * 16 + lm];
    }
#pragma unroll
    for (int rb = 0; rb < 8; ++rb)
#pragma unroll
        for (int cb = 0; cb < 4; ++cb) {
            acc[rb][cb][0] += bv[cb]; acc[rb][cb][1] += bv[cb];
            acc[rb][cb][2] += bv[cb]; acc[rb][cb][3] += bv[cb];
        }
#pragma unroll
    for (int rb = 0; rb < 8; ++rb) {
#pragma unroll
        for (int cb = 0; cb < 4; ++cb) {
            const int c = w * 64 + cb * 16 + lm;
#pragma unroll
            for (int r = 0; r < 4; ++r) {
                const int rr = row0 + rb * 16 + lg * 4 + r;
                if (rr < Nrows) Y[(size_t)rr * HD + c] = f2h(acc[rb][cb][r]);
            }
        }
    }
    // s_r for head w: reduce over this wave's 64 cols
#pragma unroll
    for (int rb = 0; rb < 8; ++rb) {
#pragma unroll
        for (int r = 0; r < 4; ++r) {
            float s = 0.f;
#pragma unroll
            for (int cb = 0; cb < 4; ++cb) {
                float p = acc[rb][cb][r] * attr[cb];
                s += p > 0.f ? p : 0.01f * p;
            }
#pragma unroll
            for (int mm = 1; mm < 16; mm <<= 1) s += __shfl_xor(s, mm);
            const int rr = row0 + rb * 16 + lg * 4 + r;
            if (lm == 0 && rr < Nrows) bw[rr * 4 + w] = __expf(s * 0.0078125f);
        }
    }
}

// ---------------- gather aggregation (one WAVE per node, f16 payload) -------
// Separable scores: result = (sum_src b[src]*h[src]) / (sum_src b[src]).
// FINAL=false: fused LayerNorm+LeakyReLU epilogue, writes f16 (N x 256).
// FINAL=true : head-mean epilogue (f32 out, N x 64).
// NOTE: no launch_bounds — VGPR 40 / ~52% occ / 8-deep load ILP is the
// measured sweet spot (R11: 65.5us; R12's (256,8) cut VGPR to 24 -> 71.6us).

template <bool FINAL>
__global__ __launch_bounds__(256) void gather_kernel(const ushort* __restrict__ hbuf,
                                                     const int* __restrict__ rp,
                                                     const int* __restrict__ col,
                                                     const float* __restrict__ bw,
                                                     const float* __restrict__ gamma,
                                                     const float* __restrict__ beta,
                                                     float* __restrict__ out,
                                                     ushort* __restrict__ ob) {
    const int t = threadIdx.x;
    const int w = t >> 6;
    const int lane = t & 63;
    const int hh = lane >> 4;
    const int n = blockIdx.x * 4 + w;

    __shared__ int cb[4][64];
    __shared__ float sv[4][256];

    const int start = rp[n], end = rp[n + 1];

    float acc0 = 0.f, acc1 = 0.f, acc2 = 0.f, acc3 = 0.f;
    float dn0 = 0.f, dn1 = 0.f, dn2 = 0.f, dn3 = 0.f;

    for (int base = start; base < end; base += 64) {
        int m = end - base;
        if (m > 64) m = 64;
        if (lane < m) {
            int src = col[base + lane];
            cb[w][lane] = src;
            float4 b4 = *(const float4*)(bw + src * 4);
            dn0 += b4.x; dn1 += b4.y; dn2 += b4.z; dn3 += b4.w;
            *(float4*)&sv[w][lane * 4] = b4;
        }
        __builtin_amdgcn_wave_barrier();
#pragma unroll 8
        for (int j = 0; j < m; ++j) {
            int src = cb[w][j];
            float s = sv[w][j * 4 + hh];
            ushort4 u = *(const ushort4*)(hbuf + (size_t)src * HD + lane * 4);
            acc0 = fmaf(h2f(u.x), s, acc0);
            acc1 = fmaf(h2f(u.y), s, acc1);
            acc2 = fmaf(h2f(u.z), s, acc2);
            acc3 = fmaf(h2f(u.w), s, acc3);
        }
        __builtin_amdgcn_wave_barrier();
    }

    // wave-total denominators per head
#pragma unroll
    for (int m2 = 32; m2 > 0; m2 >>= 1) {
        dn0 += __shfl_xor(dn0, m2);
        dn1 += __shfl_xor(dn1, m2);
        dn2 += __shfl_xor(dn2, m2);
        dn3 += __shfl_xor(dn3, m2);
    }
    float den = hh == 0 ? dn0 : hh == 1 ? dn1 : hh == 2 ? dn2 : dn3;
    float inv = 1.f / den;
    float r0 = acc0 * inv, r1 = acc1 * inv, r2 = acc2 * inv, r3 = acc3 * inv;

    if (!FINAL) {
        // fused LayerNorm + LeakyReLU over the 256-elem row held by this wave
        float s = r0 + r1 + r2 + r3;
#pragma unroll
        for (int m2 = 32; m2 > 0; m2 >>= 1) s += __shfl_xor(s, m2);
        float mu = s * (1.f / 256.f);
        float d0 = r0 - mu, d1 = r1 - mu, d2 = r2 - mu, d3 = r3 - mu;
        float vs = d0 * d0 + d1 * d1 + d2 * d2 + d3 * d3;
#pragma unroll
        for (int m2 = 32; m2 > 0; m2 >>= 1) vs += __shfl_xor(vs, m2);
        float rs = rsqrtf(vs * (1.f / 256.f) + 1e-5f);
        float4 g = *(const float4*)(gamma + lane * 4);
        float4 bb = *(const float4*)(beta + lane * 4);
        float y0 = d0 * rs * g.x + bb.x;
        float y1 = d1 * rs * g.y + bb.y;
        float y2 = d2 * rs * g.z + bb.z;
        float y3 = d3 * rs * g.w + bb.w;
        y0 = y0 > 0.f ? y0 : 0.01f * y0;
        y1 = y1 > 0.f ? y1 : 0.01f * y1;
        y2 = y2 > 0.f ? y2 : 0.01f * y2;
        y3 = y3 > 0.f ? y3 : 0.01f * y3;
        ushort4 h;
        h.x = f2h(y0); h.y = f2h(y1); h.z = f2h(y2); h.w = f2h(y3);
        *(ushort4*)(ob + (size_t)n * HD + lane * 4) = h;
    } else {
        // head-mean: lanes {c, c+16, c+32, c+48} hold same d-block, diff heads
        r0 += __shfl_xor(r0, 16); r0 += __shfl_xor(r0, 32);
        r1 += __shfl_xor(r1, 16); r1 += __shfl_xor(r1, 32);
        r2 += __shfl_xor(r2, 16); r2 += __shfl_xor(r2, 32);
        r3 += __shfl_xor(r3, 16); r3 += __shfl_xor(r3, 32);
        if (lane < 16) {
            *(float4*)(out + (size_t)n * DD + lane * 4) =
                make_float4(r0 * 0.25f, r1 * 0.25f, r2 * 0.25f, r3 * 0.25f);
        }
    }
}

// ---------------- launch ----------------

extern "C" void kernel_launch(void* const* d_in, const int* in_sizes, int n_in,
                              void* d_out, int out_size, void* d_ws, size_t ws_size,
                              hipStream_t stream) {
    const float* x     = (const float*)d_in[0];
    const int*   ei    = (const int*)d_in[1];   // (2, E): e0 then e1
    const float* W0    = (const float*)d_in[2];
    const float* b0    = (const float*)d_in[3];
    const float* W1    = (const float*)d_in[4];
    const float* b1    = (const float*)d_in[5];
    const float* att0  = (const float*)d_in[6];
    const float* att1  = (const float*)d_in[7];
    const float* gamma = (const float*)d_in[8];
    const float* beta  = (const float*)d_in[9];
    float* out = (float*)d_out;

    const int N = NN, E = EE;

    // workspace layout (~70 MB)
    ushort* ab  = (ushort*)d_ws;                  // N*256 f16 (LN output)
    ushort* hb0 = ab + (size_t)N * HD;            // N*256 f16 (h0)
    ushort* hb1 = hb0 + (size_t)N * HD;           // N*256 f16 (h1); aliases xf
    ushort* xf  = hb1;                            // N*128 f16 (dead before h1 written)
    ushort* w0f = hb1 + (size_t)N * HD;           // 256*128 f16
    ushort* w1f = w0f + HD * DIN;                 // 256*256 f16
    float* bw   = (float*)(w1f + HD * HD);        // N*4 (per-node per-head exp(s_r/128))
    int*   cnt  = (int*)(bw + (size_t)N * HH);    // N
    int*   rp   = cnt + N;                        // N+1
    int*   cur  = rp + N + 1;                     // N
    int*   col  = cur + N;                        // E
    int*   incl = col + E;                        // N
    int*   tot  = incl + N;                       // 64

    const int* e0 = ei;
    const int* e1 = ei + E;

    const int NB = (N + 1023) / 1024;  // 49

    // prep: zero cnt, then fused {histogram + f16 converts}
    hipMemsetAsync(cnt, 0, N * sizeof(int), stream);
    prep_kernel<<<HB + CB, 256, 0, stream>>>(e0, cnt, x, xf, W0, w0f, W1, w1f);
    scanA_kernel<<<NB, 1024, 0, stream>>>(cnt, incl, tot, N);
    scanC_kernel<<<(N + 255) / 256, 256, 0, stream>>>(incl, tot, cnt, rp, cur, N);
    scatter_kernel<<<(E + 255) / 256, 256, 0, stream>>>(e0, e1, cur, col, E);

    const int GB = (N + 127) / 128;  // 391 blocks, 128 rows each

    // layer 0
    gemm_mfma<DIN><<<GB, 256, 0, stream>>>(xf, w0f, b0, att0, hb0, bw, N);
    gather_kernel<false><<<N / 4, 256, 0, stream>>>(hb0, rp, col, bw, gamma, beta,
                                                    nullptr, ab);

    // layer 1
    gemm_mfma<HD><<<GB, 256, 0, stream>>>(ab, w1f, b1, att1, hb1, bw, N);
    gather_kernel<true><<<N / 4, 256, 0, stream>>>(hb1, rp, col, bw, gamma, beta,
                                                   out, nullptr);
}

// Round 14
// 274.696 us; speedup vs baseline: 1.0710x; 1.0710x over previous
//
#include <hip/hip_runtime.h>
#include <hip/hip_bf16.h>
#include <type_traits>

// Problem constants
#define NN 50000
#define EE 800000
#define HH 4
#define DD 64
#define HD 256
#define DIN 128

typedef _Float16 f16x8 __attribute__((ext_vector_type(8)));
typedef float f32x4 __attribute__((ext_vector_type(4)));

__device__ inline ushort f2h(float x) {
    _Float16 h = (_Float16)x;
    return __builtin_bit_cast(ushort, h);
}
__device__ inline float h2f(ushort u) {
    return (float)__builtin_bit_cast(_Float16, u);
}

// async global->LDS, 16B per lane; LDS base must be wave-uniform, global per-lane
__device__ inline void gload16(const ushort* src, ushort* lds_dst) {
    __builtin_amdgcn_global_load_lds(
        (const __attribute__((address_space(1))) void*)src,
        (__attribute__((address_space(3))) void*)lds_dst, 16, 0, 0);
}

// ---------------- fused prep: edge histogram + f32->f16 converts ----------------
// blocks [0, HB): histogram of e0 into cnt (cnt pre-zeroed)
// blocks [HB, HB+CB): convert x -> xf, W0 -> w0f, W1 -> w1f (float4 granules)

#define HB 3125                      // (EE+255)/256
#define NX4 (NN * DIN / 4)           // 1,600,000
#define NW04 (HD * DIN / 4)          // 8,192
#define NW14 (HD * HD / 4)           // 16,384
#define CB ((NX4 + NW04 + NW14 + 255) / 256)  // 6,346

__global__ void prep_kernel(const int* __restrict__ e0, int* __restrict__ cnt,
                            const float* __restrict__ x, ushort* __restrict__ xf,
                            const float* __restrict__ W0, ushort* __restrict__ w0f,
                            const float* __restrict__ W1, ushort* __restrict__ w1f) {
    const int b = blockIdx.x;
    if (b < HB) {
        int i = b * 256 + threadIdx.x;
        if (i < EE) atomicAdd(&cnt[e0[i]], 1);
        return;
    }
    int i = (b - HB) * 256 + threadIdx.x;
    const float* src;
    ushort* dst;
    if (i < NX4) {
        src = x; dst = xf;
    } else if (i < NX4 + NW04) {
        i -= NX4; src = W0; dst = w0f;
    } else {
        i -= NX4 + NW04;
        if (i >= NW14) return;
        src = W1; dst = w1f;
    }
    float4 v = ((const float4*)src)[i];
    ushort4 h;
    h.x = f2h(v.x); h.y = f2h(v.y); h.z = f2h(v.z); h.w = f2h(v.w);
    ((ushort4*)dst)[i] = h;
}

// ---------------- CSR scan ----------------

__global__ __launch_bounds__(1024) void scanA_kernel(const int* __restrict__ cnt,
                                                     int* __restrict__ incl,
                                                     int* __restrict__ tot, int N) {
    __shared__ int buf[2][1024];
    int b = blockIdx.x, t = threadIdx.x;
    int i = b * 1024 + t;
    int v = (i < N) ? cnt[i] : 0;
    buf[0][t] = v;
    __syncthreads();
    int sel = 0;
    for (int off = 1; off < 1024; off <<= 1) {
        int nv = buf[sel][t];
        if (t >= off) nv += buf[sel][t - off];
        buf[sel ^ 1][t] = nv;
        __syncthreads();
        sel ^= 1;
    }
    if (i < N) incl[i] = buf[sel][t];
    if (t == 1023) tot[b] = buf[sel][1023];
}

// scanC: adds inline prefix of block totals (<=48 L2-hot adds per thread)
__global__ void scanC_kernel(const int* __restrict__ incl, const int* __restrict__ tot,
                             const int* __restrict__ cnt, int* __restrict__ rp,
                             int* __restrict__ cur, int N) {
    int i = blockIdx.x * 256 + threadIdx.x;
    if (i == 0) rp[0] = 0;
    if (i < N) {
        int blk = i >> 10;
        int off = 0;
        for (int b = 0; b < blk; ++b) off += tot[b];
        int e = incl[i] + off;
        rp[i + 1] = e;
        cur[i] = e - cnt[i];
    }
}

// ---------------- MFMA GEMM (f16) + fused right-score epilogue ----------------
// Y[n][m] = sum_k A[n][k]*W[m][k] + b[m]   (f16 operands, f32 accum)
// bw[n][h] = exp( (sum_d lrelu(Y[n][h*64+d]*att_r[h][d])) / 128 )
// Block: 64 rows x 256 cols, BK=32, double-buffered LDS (2x20KB), col-split
// waves (wave w owns cols [w*64,w*64+64) = head w). T3/T4 pipeline:
// STAGE(next) -> s_waitcnt vmcnt(5) (counted: 5 loads/wave/tile) -> s_barrier
// -> COMPUTE(cur) -> s_barrier. LDS layout [kchunk(4)][row][8k]: linear for
// global_load_lds, conflict-free for ds_read_b128 fragments.
// (64-row tile is the measured optimum: R13's 128-row tile cost +14us from
//  occupancy loss at 48KB LDS / ~190 VGPR.)
// FUSE_SCATTER: blocks [GB, GB+HB) run the CSR scatter instead (independent
// work co-scheduled under the GEMM — overlaps atomic/memory traffic with MFMA).

template <int K, bool FUSE_SCATTER>
__global__ __launch_bounds__(256) void gemm_mfma(const ushort* __restrict__ A,
                                                 const ushort* __restrict__ B,
                                                 const float* __restrict__ bias,
                                                 const float* __restrict__ att,
                                                 ushort* __restrict__ Y,
                                                 float* __restrict__ bw,
                                                 int Nrows, int GB,
                                                 const int* __restrict__ e0,
                                                 const int* __restrict__ e1,
                                                 int* __restrict__ cur2,
                                                 int* __restrict__ colv) {
    if constexpr (FUSE_SCATTER) {
        if (blockIdx.x >= GB) {
            int i = (blockIdx.x - GB) * 256 + threadIdx.x;
            if (i < EE) {
                int pos = atomicAdd(&cur2[e0[i]], 1);
                colv[pos] = e1[i];
            }
            return;
        }
    }

    __shared__ ushort sh[2][10240];  // per buf: A[4][64][8] (2048) + B[4][256][8] (8192)

    const int t = threadIdx.x;
    const int w = t >> 6, lane = t & 63;
    const int lg = lane >> 4;
    const int lm = lane & 15;
    const int row0 = blockIdx.x * 64;

    f32x4 acc[4][4];  // [rowblock][colblock]; cols = w*64 + cb*16 + lm
#pragma unroll
    for (int rb = 0; rb < 4; ++rb)
#pragma unroll
        for (int cb = 0; cb < 4; ++cb) acc[rb][cb] = (f32x4){0.f, 0.f, 0.f, 0.f};

    auto STAGE = [&](int b, int ks) {  // 5 global_load_lds per wave
        const int k0 = ks * 32;
        ushort* base = sh[b];
        gload16(A + (size_t)(row0 + lane) * K + k0 + w * 8, base + w * 512);
#pragma unroll
        for (int j2 = 0; j2 < 4; ++j2)
            gload16(B + (size_t)(j2 * 64 + lane) * K + k0 + w * 8,
                    base + 2048 + w * 2048 + j2 * 512);
    };
    auto COMPUTE = [&](int b) {
        ushort* base = sh[b];
        f16x8 a_h[4], b_h[4];
#pragma unroll
        for (int rb = 0; rb < 4; ++rb)
            a_h[rb] = *(const f16x8*)(base + lg * 512 + (rb * 16 + lm) * 8);
#pragma unroll
        for (int cb = 0; cb < 4; ++cb) {
            const int c = w * 64 + cb * 16 + lm;
            b_h[cb] = *(const f16x8*)(base + 2048 + lg * 2048 + c * 8);
        }
#pragma unroll
        for (int rb = 0; rb < 4; ++rb)
#pragma unroll
            for (int cb = 0; cb < 4; ++cb)
                acc[rb][cb] = __builtin_amdgcn_mfma_f32_16x16x32_f16(
                    a_h[rb], b_h[cb], acc[rb][cb], 0, 0, 0);
    };

    constexpr int NT = K / 32;
    STAGE(0, 0);
#pragma unroll
    for (int ks = 0; ks < NT; ++ks) {
        const int cb_ = ks & 1;
        if (ks + 1 < NT) {
            STAGE(cb_ ^ 1, ks + 1);
            asm volatile("s_waitcnt vmcnt(5)" ::: "memory");  // cur tile landed
        } else {
            asm volatile("s_waitcnt vmcnt(0)" ::: "memory");
        }
        __builtin_amdgcn_s_barrier();
        COMPUTE(cb_);
        __builtin_amdgcn_s_barrier();  // reads done before next STAGE overwrites
    }

    // ---- epilogue: bias, f16 store, fused right-scores (wave w = head w) ----
    float attr[4], bv[4];
#pragma unroll
    for (int cb = 0; cb < 4; ++cb) {
        attr[cb] = att[w * 128 + 64 + cb * 16 + lm];
        bv[cb] = bias[w * 64 + cb * 16 + lm];
    }
#pragma unroll
    for (int rb = 0; rb < 4; ++rb)
#pragma unroll
        for (int cb = 0; cb < 4; ++cb) {
            acc[rb][cb][0] += bv[cb]; acc[rb][cb][1] += bv[cb];
            acc[rb][cb][2] += bv[cb]; acc[rb][cb][3] += bv[cb];
        }
#pragma unroll
    for (int rb = 0; rb < 4; ++rb) {
#pragma unroll
        for (int cb = 0; cb < 4; ++cb) {
            const int c = w * 64 + cb * 16 + lm;
#pragma unroll
            for (int r = 0; r < 4; ++r) {
                const int rr = row0 + rb * 16 + lg * 4 + r;
                if (rr < Nrows) Y[(size_t)rr * HD + c] = f2h(acc[rb][cb][r]);
            }
        }
    }
    // s_r for head w: reduce over this wave's 64 cols
#pragma unroll
    for (int rb = 0; rb < 4; ++rb) {
#pragma unroll
        for (int r = 0; r < 4; ++r) {
            float s = 0.f;
#pragma unroll
            for (int cb = 0; cb < 4; ++cb) {
                float p = acc[rb][cb][r] * attr[cb];
                s += p > 0.f ? p : 0.01f * p;
            }
#pragma unroll
            for (int mm = 1; mm < 16; mm <<= 1) s += __shfl_xor(s, mm);
            const int rr = row0 + rb * 16 + lg * 4 + r;
            if (lm == 0 && rr < Nrows) bw[rr * 4 + w] = __expf(s * 0.0078125f);
        }
    }
}

// ---------------- gather aggregation (one WAVE per node, f16 payload) -------
// Separable scores: result = (sum_src b[src]*h[src]) / (sum_src b[src]).
// FINAL=false: fused LayerNorm+LeakyReLU epilogue, writes f16 (N x 256).
// FINAL=true : head-mean epilogue (f32 out, N x 64).
// NOTE: no launch_bounds — VGPR 40 / ~52% occ / 8-deep load ILP is the
// measured sweet spot (R11/R13: 65us; R12's (256,8) cut VGPR to 24 -> 71.6us).

template <bool FINAL>
__global__ __launch_bounds__(256) void gather_kernel(const ushort* __restrict__ hbuf,
                                                     const int* __restrict__ rp,
                                                     const int* __restrict__ col,
                                                     const float* __restrict__ bw,
                                                     const float* __restrict__ gamma,
                                                     const float* __restrict__ beta,
                                                     float* __restrict__ out,
                                                     ushort* __restrict__ ob) {
    const int t = threadIdx.x;
    const int w = t >> 6;
    const int lane = t & 63;
    const int hh = lane >> 4;
    const int n = blockIdx.x * 4 + w;

    __shared__ int cb[4][64];
    __shared__ float sv[4][256];

    const int start = rp[n], end = rp[n + 1];

    float acc0 = 0.f, acc1 = 0.f, acc2 = 0.f, acc3 = 0.f;
    float dn0 = 0.f, dn1 = 0.f, dn2 = 0.f, dn3 = 0.f;

    for (int base = start; base < end; base += 64) {
        int m = end - base;
        if (m > 64) m = 64;
        if (lane < m) {
            int src = col[base + lane];
            cb[w][lane] = src;
            float4 b4 = *(const float4*)(bw + src * 4);
            dn0 += b4.x; dn1 += b4.y; dn2 += b4.z; dn3 += b4.w;
            *(float4*)&sv[w][lane * 4] = b4;
        }
        __builtin_amdgcn_wave_barrier();
#pragma unroll 8
        for (int j = 0; j < m; ++j) {
            int src = cb[w][j];
            float s = sv[w][j * 4 + hh];
            ushort4 u = *(const ushort4*)(hbuf + (size_t)src * HD + lane * 4);
            acc0 = fmaf(h2f(u.x), s, acc0);
            acc1 = fmaf(h2f(u.y), s, acc1);
            acc2 = fmaf(h2f(u.z), s, acc2);
            acc3 = fmaf(h2f(u.w), s, acc3);
        }
        __builtin_amdgcn_wave_barrier();
    }

    // wave-total denominators per head
#pragma unroll
    for (int m2 = 32; m2 > 0; m2 >>= 1) {
        dn0 += __shfl_xor(dn0, m2);
        dn1 += __shfl_xor(dn1, m2);
        dn2 += __shfl_xor(dn2, m2);
        dn3 += __shfl_xor(dn3, m2);
    }
    float den = hh == 0 ? dn0 : hh == 1 ? dn1 : hh == 2 ? dn2 : dn3;
    float inv = 1.f / den;
    float r0 = acc0 * inv, r1 = acc1 * inv, r2 = acc2 * inv, r3 = acc3 * inv;

    if (!FINAL) {
        // fused LayerNorm + LeakyReLU over the 256-elem row held by this wave
        float s = r0 + r1 + r2 + r3;
#pragma unroll
        for (int m2 = 32; m2 > 0; m2 >>= 1) s += __shfl_xor(s, m2);
        float mu = s * (1.f / 256.f);
        float d0 = r0 - mu, d1 = r1 - mu, d2 = r2 - mu, d3 = r3 - mu;
        float vs = d0 * d0 + d1 * d1 + d2 * d2 + d3 * d3;
#pragma unroll
        for (int m2 = 32; m2 > 0; m2 >>= 1) vs += __shfl_xor(vs, m2);
        float rs = rsqrtf(vs * (1.f / 256.f) + 1e-5f);
        float4 g = *(const float4*)(gamma + lane * 4);
        float4 bb = *(const float4*)(beta + lane * 4);
        float y0 = d0 * rs * g.x + bb.x;
        float y1 = d1 * rs * g.y + bb.y;
        float y2 = d2 * rs * g.z + bb.z;
        float y3 = d3 * rs * g.w + bb.w;
        y0 = y0 > 0.f ? y0 : 0.01f * y0;
        y1 = y1 > 0.f ? y1 : 0.01f * y1;
        y2 = y2 > 0.f ? y2 : 0.01f * y2;
        y3 = y3 > 0.f ? y3 : 0.01f * y3;
        ushort4 h;
        h.x = f2h(y0); h.y = f2h(y1); h.z = f2h(y2); h.w = f2h(y3);
        *(ushort4*)(ob + (size_t)n * HD + lane * 4) = h;
    } else {
        // head-mean: lanes {c, c+16, c+32, c+48} hold same d-block, diff heads
        r0 += __shfl_xor(r0, 16); r0 += __shfl_xor(r0, 32);
        r1 += __shfl_xor(r1, 16); r1 += __shfl_xor(r1, 32);
        r2 += __shfl_xor(r2, 16); r2 += __shfl_xor(r2, 32);
        r3 += __shfl_xor(r3, 16); r3 += __shfl_xor(r3, 32);
        if (lane < 16) {
            *(float4*)(out + (size_t)n * DD + lane * 4) =
                make_float4(r0 * 0.25f, r1 * 0.25f, r2 * 0.25f, r3 * 0.25f);
        }
    }
}

// ---------------- launch ----------------

extern "C" void kernel_launch(void* const* d_in, const int* in_sizes, int n_in,
                              void* d_out, int out_size, void* d_ws, size_t ws_size,
                              hipStream_t stream) {
    const float* x     = (const float*)d_in[0];
    const int*   ei    = (const int*)d_in[1];   // (2, E): e0 then e1
    const float* W0    = (const float*)d_in[2];
    const float* b0    = (const float*)d_in[3];
    const float* W1    = (const float*)d_in[4];
    const float* b1    = (const float*)d_in[5];
    const float* att0  = (const float*)d_in[6];
    const float* att1  = (const float*)d_in[7];
    const float* gamma = (const float*)d_in[8];
    const float* beta  = (const float*)d_in[9];
    float* out = (float*)d_out;

    const int N = NN, E = EE;

    // workspace layout (~70 MB)
    ushort* ab  = (ushort*)d_ws;                  // N*256 f16 (LN output)
    ushort* hb0 = ab + (size_t)N * HD;            // N*256 f16 (h0)
    ushort* hb1 = hb0 + (size_t)N * HD;           // N*256 f16 (h1); aliases xf
    ushort* xf  = hb1;                            // N*128 f16 (dead before h1 written)
    ushort* w0f = hb1 + (size_t)N * HD;           // 256*128 f16
    ushort* w1f = w0f + HD * DIN;                 // 256*256 f16
    float* bw   = (float*)(w1f + HD * HD);        // N*4 (per-node per-head exp(s_r/128))
    int*   cnt  = (int*)(bw + (size_t)N * HH);    // N
    int*   rp   = cnt + N;                        // N+1
    int*   cur  = rp + N + 1;                     // N
    int*   col  = cur + N;                        // E
    int*   incl = col + E;                        // N
    int*   tot  = incl + N;                       // 64

    const int* e0 = ei;
    const int* e1 = ei + E;

    const int NB = (N + 1023) / 1024;  // 49

    // prep: zero cnt, then fused {histogram + f16 converts}
    hipMemsetAsync(cnt, 0, N * sizeof(int), stream);
    prep_kernel<<<HB + CB, 256, 0, stream>>>(e0, cnt, x, xf, W0, w0f, W1, w1f);
    scanA_kernel<<<NB, 1024, 0, stream>>>(cnt, incl, tot, N);
    scanC_kernel<<<(N + 255) / 256, 256, 0, stream>>>(incl, tot, cnt, rp, cur, N);

    const int GB = (N + 63) / 64;  // 782 blocks, 64 rows each

    // layer 0 GEMM fused with CSR scatter (independent work, co-scheduled)
    gemm_mfma<DIN, true><<<GB + HB, 256, 0, stream>>>(xf, w0f, b0, att0, hb0, bw, N,
                                                      GB, e0, e1, cur, col);
    gather_kernel<false><<<N / 4, 256, 0, stream>>>(hb0, rp, col, bw, gamma, beta,
                                                    nullptr, ab);

    // layer 1
    gemm_mfma<HD, false><<<GB, 256, 0, stream>>>(ab, w1f, b1, att1, hb1, bw, N,
                                                 GB, nullptr, nullptr, nullptr, nullptr);
    gather_kernel<true><<<N / 4, 256, 0, stream>>>(hb1, rp, col, bw, gamma, beta,
                                                   out, nullptr);
}